// Round 8
// baseline (484.711 us; speedup 1.0000x reference)
//
#include <hip/hip_runtime.h>

#define T_TOK 4096
#define HDIM  1024
#define NEXP  8
#define FFDIM 4096
#define NPAIR 8192   // T_TOK * topk
#define MAXMT 40     // max total 256-row M-tiles across experts: 8192/256 + 8

typedef __attribute__((ext_vector_type(8))) short short8;
typedef __attribute__((ext_vector_type(8))) unsigned short ushort8;
typedef __attribute__((ext_vector_type(4))) float f32x4;

__device__ __forceinline__ unsigned short f2bf(float f) {
  unsigned int u = __float_as_uint(f);
  u += 0x7fffu + ((u >> 16) & 1u);   // RNE
  return (unsigned short)(u >> 16);
}

// global -> LDS direct copy, 16B per lane. LDS dest is wave-uniform base;
// HW writes lane l at base + l*16. Global source address is per-lane.
__device__ __forceinline__ void gload16(const void* g, const void* l) {
  __builtin_amdgcn_global_load_lds(
      (const __attribute__((address_space(1))) unsigned int*)(unsigned long long)g,
      (__attribute__((address_space(3))) unsigned int*)(unsigned int)(unsigned long long)l,
      16, 0, 0);
}

// ---------------- conversions ----------------

__global__ __launch_bounds__(256) void convert_x_kernel(
    const float* __restrict__ in, unsigned short* __restrict__ out) {
  int i = (blockIdx.x * 256 + threadIdx.x) * 8;
  float4 a = *(const float4*)(in + i);
  float4 b = *(const float4*)(in + i + 4);
  ushort8 o;
  o[0] = f2bf(a.x); o[1] = f2bf(a.y); o[2] = f2bf(a.z); o[3] = f2bf(a.w);
  o[4] = f2bf(b.x); o[5] = f2bf(b.y); o[6] = f2bf(b.z); o[7] = f2bf(b.w);
  *(ushort8*)(out + i) = o;
}

// [M][N] fp32 -> [N][M] bf16, per-expert (blockIdx.z), 64x64 tiles
__global__ __launch_bounds__(256) void transpose_bf16_kernel(
    const float* __restrict__ in, unsigned short* __restrict__ out, int M, int N) {
  in  += (size_t)blockIdx.z * M * N;
  out += (size_t)blockIdx.z * M * N;
  __shared__ unsigned short t[64][72];
  int tid = threadIdx.x;
  int r0 = blockIdx.y * 64, c0 = blockIdx.x * 64;
#pragma unroll
  for (int rr = 0; rr < 4; rr++) {
    int row = rr * 16 + (tid >> 4);
    int col = (tid & 15) * 4;
    float4 v = *(const float4*)(in + (size_t)(r0 + row) * N + c0 + col);
    t[col + 0][row] = f2bf(v.x);
    t[col + 1][row] = f2bf(v.y);
    t[col + 2][row] = f2bf(v.z);
    t[col + 3][row] = f2bf(v.w);
  }
  __syncthreads();
#pragma unroll
  for (int rr = 0; rr < 2; rr++) {
    int c = rr * 32 + (tid >> 3);
    int m0 = (tid & 7) * 8;
    ushort8 v = *(const ushort8*)&t[c][m0];
    *(ushort8*)(out + (size_t)(c0 + c) * M + r0 + m0) = v;
  }
}

// ---------------- router ----------------

__global__ __launch_bounds__(256) void router_kernel(
    const float* __restrict__ x, const float* __restrict__ wg,
    int* __restrict__ sel_e, float* __restrict__ sel_w, int* __restrict__ counts) {
  int lane = threadIdx.x & 63;
  int t = blockIdx.x * 4 + (threadIdx.x >> 6);
  const float* xr = x + (size_t)t * HDIM;
  float acc[8] = {0, 0, 0, 0, 0, 0, 0, 0};
  for (int i = 0; i < HDIM / 64; i++) {
    int h = i * 64 + lane;
    float xv = xr[h];
    float4 w0 = *(const float4*)(wg + h * 8);
    float4 w1 = *(const float4*)(wg + h * 8 + 4);
    acc[0] += xv * w0.x; acc[1] += xv * w0.y; acc[2] += xv * w0.z; acc[3] += xv * w0.w;
    acc[4] += xv * w1.x; acc[5] += xv * w1.y; acc[6] += xv * w1.z; acc[7] += xv * w1.w;
  }
#pragma unroll
  for (int off = 32; off > 0; off >>= 1) {
#pragma unroll
    for (int e = 0; e < 8; e++) acc[e] += __shfl_xor(acc[e], off, 64);
  }
  if (lane == 0) {
    int e0 = 0; float b0 = acc[0];
#pragma unroll
    for (int e = 1; e < 8; e++) if (acc[e] > b0) { b0 = acc[e]; e0 = e; }
    int e1 = -1; float b1 = -3.4e38f;
#pragma unroll
    for (int e = 0; e < 8; e++) if (e != e0 && acc[e] > b1) { b1 = acc[e]; e1 = e; }
    float q = expf(b1 - b0);                 // softmax denominator cancels in renorm
    float w0 = 1.0f / (1.0f + q);
    float w1 = q / (1.0f + q);
    sel_e[t * 2] = e0; sel_e[t * 2 + 1] = e1;
    sel_w[t * 2] = w0; sel_w[t * 2 + 1] = w1;
    atomicAdd(&counts[e0], 1);
    atomicAdd(&counts[e1], 1);
  }
}

__global__ void offsets_kernel(const int* __restrict__ counts,
                               int* __restrict__ offsets, int* __restrict__ cursor) {
  if (threadIdx.x == 0 && blockIdx.x == 0) {
    int s = 0;
    for (int e = 0; e < NEXP; e++) { offsets[e] = s; cursor[e] = s; s += counts[e]; }
  }
}

__global__ __launch_bounds__(256) void scatter_kernel(
    const int* __restrict__ sel_e, const float* __restrict__ sel_w,
    int* __restrict__ cursor, int* __restrict__ pair_token, float* __restrict__ pair_w) {
  int t = blockIdx.x * 256 + threadIdx.x;
#pragma unroll
  for (int j = 0; j < 2; j++) {
    int e = sel_e[t * 2 + j];
    int pos = atomicAdd(&cursor[e], 1);
    pair_token[pos] = t;
    pair_w[pos] = sel_w[t * 2 + j];
  }
}

// --- expert GEMMs: 256x256, BK=64, 2-slot dbuf (128KB), 8 waves, 2-phase tiles ---
// Wave grid 2M x 4N, wave tile 128x64, acc[8][4]. Per K-tile:
//  P0: stage t+1 A-half (4 gload16) -> vmcnt(4) [own: 4 newest = t+1-A, so ALL of
//      tile t landed] -> s_barrier [makes it global: every wave vmcnt'd before]
//      -> kk0 reads (12 ds_read_b128) -> setprio 32 MFMA.
//  P1: stage t+1 B-half -> kk1 reads -> setprio 32 MFMA -> end barrier [WAR:
//      next iter stages into buf^1 only after ALL waves finished reading it].
// Last tile: vmcnt(0) (nothing newer in flight - round-3/4 lesson).
// Round-7 NaN post-mortem: vmcnt AFTER the barrier only proves the wave's OWN
// loads landed; other waves' stages into the region it reads were not ordered.
// vmcnt must precede the barrier. WAR on 2 slots needs the end-of-tile barrier.
// Swizzle (round-5 pair, measured 0 conflicts): 128B rows = 8 chunks of 16B;
// store chunk (tid&7)^(srow&7), read chunk c at slot c^(lr&7).
// Work order: w = (nt*KSPL+ks)*MAXMT + mt, XCD-chunked (nb%8==0, bijective):
// within an XCD consecutive blocks share one B-panel (512KB, L2-resident).
template <int KD, int KSPL, int NT, bool GATHER, bool SQRELU>
__global__ __launch_bounds__(512, 1) void moe_gemm_kernel(
    const unsigned short* __restrict__ A0, const unsigned short* __restrict__ B0,
    const int* __restrict__ counts,
    const int* __restrict__ pair_token, const float* __restrict__ pair_w,
    unsigned short* __restrict__ h1out, float* __restrict__ out) {
  constexpr int ND = SQRELU ? FFDIM : HDIM;
  constexpr int KLEN = KD / KSPL;
  constexpr int NTILES = KLEN / 64;

  // XCD-chunked bijective swizzle (gridDim.x % 8 == 0)
  int d = blockIdx.x;
  int nb = gridDim.x;
  int w = (d & 7) * (nb >> 3) + (d >> 3);
  int mt = w % MAXMT;
  int rest = w / MAXMT;
  int ks = rest % KSPL;
  int nt = rest / KSPL;

  // ---- expert-tile search (wave-uniform) ----
  int eSel = -1, tloc = 0, segstart = 0, segcnt = 0;
  {
    int cumt = 0, acc = 0;
#pragma unroll
    for (int ee = 0; ee < NEXP; ee++) {
      int c = counts[ee];
      int ntl = (c + 255) >> 8;
      if (eSel < 0 && mt < cumt + ntl) { eSel = ee; tloc = mt - cumt; segstart = acc; segcnt = c; }
      cumt += ntl; acc += c;
    }
  }
  if (eSel < 0) return;

  const unsigned short* B = B0 + (size_t)eSel * ND * KD + (size_t)ks * KLEN;
  const unsigned short* Abase = A0 + (size_t)ks * KLEN;

  int tid = threadIdx.x;
  int lane = tid & 63;
  int wv = tid >> 6;       // 0..7
  int wr = wv >> 2;        // 0..1  (M: rows wr*128..+127)
  int wc = wv & 3;         // 0..3  (N: cols wc*64..+63)
  int g  = lane >> 4;      // 0..3
  int lr = lane & 15;

  // staging: line r covers rows r*64 + (tid>>3); 8 threads per 128B row
  int srow = tid >> 3;                       // 0..63
  int schunk = (tid & 7) ^ (srow & 7);       // pre-swizzled source chunk
  const unsigned short* aP[4];
  const unsigned short* bP[4];
#pragma unroll
  for (int r = 0; r < 4; r++) {
    int arow = r * 64 + srow;
    int idx = tloc * 256 + arow;
    if (idx >= segcnt) idx = segcnt - 1;     // clamp pad rows
    int p = segstart + idx;
    size_t rowoff;
    if (GATHER) rowoff = (size_t)pair_token[p] * KD;
    else        rowoff = (size_t)p * KD;
    aP[r] = Abase + rowoff + schunk * 8;
    bP[r] = B + (size_t)(nt * 256 + arow) * KD + schunk * 8;
  }

  __shared__ char lds[131072];         // 2 x (A 32KB + B 32KB)
  const char* ldsc = lds;
  int ldsW = wv * 1024;                // wave-uniform (lane*16 added by HW)

  f32x4 acc[8][4];
#pragma unroll
  for (int i = 0; i < 8; i++)
#pragma unroll
    for (int j = 0; j < 4; j++) acc[i][j] = (f32x4){0.f, 0.f, 0.f, 0.f};

  // prologue: stage tile 0 into buf 0
#pragma unroll
  for (int r = 0; r < 4; r++) gload16(aP[r], ldsc + r * 8192 + ldsW);
#pragma unroll
  for (int r = 0; r < 4; r++) gload16(bP[r], ldsc + 32768 + r * 8192 + ldsW);
#pragma unroll
  for (int r = 0; r < 4; r++) { aP[r] += 64; bP[r] += 64; }

  int cur = 0;
  for (int t = 0; t < NTILES; ++t) {
    const char* bufA = ldsc + cur * 65536;
    const char* bufB = bufA + 32768;
    int so = (cur ^ 1) * 65536;
    bool pf = (t + 1 < NTILES);

    // ---- phase 0: stage t+1 A-half; wait tile t; kk=0 compute ----
    if (pf) {
#pragma unroll
      for (int r = 0; r < 4; r++) gload16(aP[r], ldsc + so + r * 8192 + ldsW);
      asm volatile("s_waitcnt vmcnt(4)" ::: "memory");   // tile t fully landed (own)
    } else {
      asm volatile("s_waitcnt vmcnt(0)" ::: "memory");   // final tile: drain all
    }
    __builtin_amdgcn_s_barrier();        // global: every wave's vmcnt preceded this
    __builtin_amdgcn_sched_barrier(0);

    short8 af[8], bf[4];
    {
      int swz = (g ^ (lr & 7)) * 16;
#pragma unroll
      for (int mi = 0; mi < 8; mi++)
        af[mi] = *(const short8*)(bufA + (wr * 128 + mi * 16 + lr) * 128 + swz);
#pragma unroll
      for (int nj = 0; nj < 4; nj++)
        bf[nj] = *(const short8*)(bufB + (wc * 64 + nj * 16 + lr) * 128 + swz);
    }
    __builtin_amdgcn_s_setprio(1);
#pragma unroll
    for (int mi = 0; mi < 8; mi++)
#pragma unroll
      for (int nj = 0; nj < 4; nj++)
        acc[mi][nj] = __builtin_amdgcn_mfma_f32_16x16x32_bf16(af[mi], bf[nj], acc[mi][nj], 0, 0, 0);
    __builtin_amdgcn_s_setprio(0);

    // ---- phase 1: stage t+1 B-half; kk=1 compute; end-of-tile barrier ----
    if (pf) {
#pragma unroll
      for (int r = 0; r < 4; r++) gload16(bP[r], ldsc + so + 32768 + r * 8192 + ldsW);
#pragma unroll
      for (int r = 0; r < 4; r++) { aP[r] += 64; bP[r] += 64; }
    }
    {
      int swz = ((4 + g) ^ (lr & 7)) * 16;
#pragma unroll
      for (int mi = 0; mi < 8; mi++)
        af[mi] = *(const short8*)(bufA + (wr * 128 + mi * 16 + lr) * 128 + swz);
#pragma unroll
      for (int nj = 0; nj < 4; nj++)
        bf[nj] = *(const short8*)(bufB + (wc * 64 + nj * 16 + lr) * 128 + swz);
    }
    __builtin_amdgcn_s_setprio(1);
#pragma unroll
    for (int mi = 0; mi < 8; mi++)
#pragma unroll
      for (int nj = 0; nj < 4; nj++)
        acc[mi][nj] = __builtin_amdgcn_mfma_f32_16x16x32_bf16(af[mi], bf[nj], acc[mi][nj], 0, 0, 0);
    __builtin_amdgcn_s_setprio(0);

    __builtin_amdgcn_s_barrier();        // WAR: buf^1 free for next iter's staging
    cur ^= 1;
  }

  // ---- epilogue: C/D layout col=lane&15, row=(lane>>4)*4+q ----
  int colb = nt * 256 + wc * 64 + lr;        // + nj*16
  int rowb = tloc * 256 + wr * 128 + g * 4;  // + mi*16 + q
#pragma unroll
  for (int mi = 0; mi < 8; mi++) {
#pragma unroll
    for (int q = 0; q < 4; q++) {
      int idx = rowb + mi * 16 + q;
      if (idx < segcnt) {
        int p = segstart + idx;
        if (SQRELU) {
          size_t ro = (size_t)p * FFDIM + colb;
#pragma unroll
          for (int nj = 0; nj < 4; nj++) {
            float v = acc[mi][nj][q];
            v = v > 0.f ? v * v : 0.f;
            h1out[ro + nj * 16] = f2bf(v);
          }
        } else {
          int tok = pair_token[p];
          float wgt = pair_w[p];
          size_t ro = (size_t)tok * HDIM + colb;
#pragma unroll
          for (int nj = 0; nj < 4; nj++)
            atomicAdd(out + ro + nj * 16, acc[mi][nj][q] * wgt);
        }
      }
    }
  }
}

// ---------------- launch ----------------

extern "C" void kernel_launch(void* const* d_in, const int* in_sizes, int n_in,
                              void* d_out, int out_size, void* d_ws, size_t ws_size,
                              hipStream_t stream) {
  (void)in_sizes; (void)n_in; (void)out_size; (void)ws_size;
  const float* x     = (const float*)d_in[0];
  const float* Wg    = (const float*)d_in[1];
  const float* Wfc   = (const float*)d_in[2];
  const float* Wproj = (const float*)d_in[3];
  float* out = (float*)d_out;

  char* w = (char*)d_ws;
  size_t o = 0;
  auto take = [&](size_t n) { char* p = w + o; o += (n + 255) & ~(size_t)255; return p; };
  unsigned short* xb     = (unsigned short*)take((size_t)T_TOK * HDIM * 2);
  unsigned short* WfcT   = (unsigned short*)take((size_t)NEXP * FFDIM * HDIM * 2);
  unsigned short* WprojT = (unsigned short*)take((size_t)NEXP * HDIM * FFDIM * 2);
  unsigned short* h1     = (unsigned short*)take((size_t)NPAIR * FFDIM * 2);
  int*   sel_e      = (int*)take(T_TOK * 2 * 4);
  float* sel_w      = (float*)take(T_TOK * 2 * 4);
  int*   pair_token = (int*)take(NPAIR * 4);
  float* pair_w     = (float*)take(NPAIR * 4);
  int*   counts     = (int*)take(3 * 8 * 4);
  int*   offsets    = counts + 8;
  int*   cursor     = counts + 16;

  hipMemsetAsync(out, 0, (size_t)T_TOK * HDIM * 4, stream);
  hipMemsetAsync(counts, 0, 96, stream);

  convert_x_kernel<<<T_TOK * HDIM / (256 * 8), 256, 0, stream>>>(x, xb);
  transpose_bf16_kernel<<<dim3(FFDIM / 64, HDIM / 64, NEXP), 256, 0, stream>>>(Wfc, WfcT, HDIM, FFDIM);
  transpose_bf16_kernel<<<dim3(HDIM / 64, FFDIM / 64, NEXP), 256, 0, stream>>>(Wproj, WprojT, FFDIM, HDIM);
  router_kernel<<<T_TOK / 4, 256, 0, stream>>>(x, Wg, sel_e, sel_w, counts);
  offsets_kernel<<<1, 64, 0, stream>>>(counts, offsets, cursor);
  scatter_kernel<<<T_TOK / 256, 256, 0, stream>>>(sel_e, sel_w, cursor, pair_token, pair_w);

  // GEMM1: per expert, [seg x 1024] x [1024 x 4096] -> relu^2 -> h1 (bf16)
  moe_gemm_kernel<HDIM, 1, FFDIM / 256, true, true>
      <<<MAXMT * (FFDIM / 256), 512, 0, stream>>>(xb, WfcT, counts,
                                                  pair_token, pair_w, h1, nullptr);
  // GEMM2: per expert, [seg x 4096] x [4096 x 1024] -> weighted combine, split-K=4
  moe_gemm_kernel<FFDIM, 4, HDIM / 256, false, false>
      <<<MAXMT * (HDIM / 256) * 4, 512, 0, stream>>>(h1, WprojT, counts,
                                                     pair_token, pair_w, nullptr, out);
}

// Round 9
// 431.013 us; speedup vs baseline: 1.1246x; 1.1246x over previous
//
#include <hip/hip_runtime.h>

#define T_TOK 4096
#define HDIM  1024
#define NEXP  8
#define FFDIM 4096
#define NPAIR 8192   // T_TOK * topk
#define MAXMT 72     // max total 128-row M-tiles across experts: 8192/128 + 8

typedef __attribute__((ext_vector_type(8))) short short8;
typedef __attribute__((ext_vector_type(8))) unsigned short ushort8;
typedef __attribute__((ext_vector_type(4))) float f32x4;

__device__ __forceinline__ unsigned short f2bf(float f) {
  unsigned int u = __float_as_uint(f);
  u += 0x7fffu + ((u >> 16) & 1u);   // RNE
  return (unsigned short)(u >> 16);
}

// global -> LDS direct copy, 16B per lane. LDS dest is wave-uniform base;
// HW writes lane l at base + l*16. Global source address is per-lane.
__device__ __forceinline__ void gload16(const void* g, const void* l) {
  __builtin_amdgcn_global_load_lds(
      (const __attribute__((address_space(1))) unsigned int*)(unsigned long long)g,
      (__attribute__((address_space(3))) unsigned int*)(unsigned int)(unsigned long long)l,
      16, 0, 0);
}

// ---------------- conversions ----------------

__global__ __launch_bounds__(256) void convert_x_kernel(
    const float* __restrict__ in, unsigned short* __restrict__ out) {
  int i = (blockIdx.x * 256 + threadIdx.x) * 8;
  float4 a = *(const float4*)(in + i);
  float4 b = *(const float4*)(in + i + 4);
  ushort8 o;
  o[0] = f2bf(a.x); o[1] = f2bf(a.y); o[2] = f2bf(a.z); o[3] = f2bf(a.w);
  o[4] = f2bf(b.x); o[5] = f2bf(b.y); o[6] = f2bf(b.z); o[7] = f2bf(b.w);
  *(ushort8*)(out + i) = o;
}

// [M][N] fp32 -> [N][M] bf16, per-expert (blockIdx.z), 64x64 tiles
__global__ __launch_bounds__(256) void transpose_bf16_kernel(
    const float* __restrict__ in, unsigned short* __restrict__ out, int M, int N) {
  in  += (size_t)blockIdx.z * M * N;
  out += (size_t)blockIdx.z * M * N;
  __shared__ unsigned short t[64][72];
  int tid = threadIdx.x;
  int r0 = blockIdx.y * 64, c0 = blockIdx.x * 64;
#pragma unroll
  for (int rr = 0; rr < 4; rr++) {
    int row = rr * 16 + (tid >> 4);
    int col = (tid & 15) * 4;
    float4 v = *(const float4*)(in + (size_t)(r0 + row) * N + c0 + col);
    t[col + 0][row] = f2bf(v.x);
    t[col + 1][row] = f2bf(v.y);
    t[col + 2][row] = f2bf(v.z);
    t[col + 3][row] = f2bf(v.w);
  }
  __syncthreads();
#pragma unroll
  for (int rr = 0; rr < 2; rr++) {
    int c = rr * 32 + (tid >> 3);
    int m0 = (tid & 7) * 8;
    ushort8 v = *(const ushort8*)&t[c][m0];
    *(ushort8*)(out + (size_t)(c0 + c) * M + r0 + m0) = v;
  }
}

// ---------------- router ----------------

__global__ __launch_bounds__(256) void router_kernel(
    const float* __restrict__ x, const float* __restrict__ wg,
    int* __restrict__ sel_e, float* __restrict__ sel_w, int* __restrict__ counts) {
  int lane = threadIdx.x & 63;
  int t = blockIdx.x * 4 + (threadIdx.x >> 6);
  const float* xr = x + (size_t)t * HDIM;
  float acc[8] = {0, 0, 0, 0, 0, 0, 0, 0};
  for (int i = 0; i < HDIM / 64; i++) {
    int h = i * 64 + lane;
    float xv = xr[h];
    float4 w0 = *(const float4*)(wg + h * 8);
    float4 w1 = *(const float4*)(wg + h * 8 + 4);
    acc[0] += xv * w0.x; acc[1] += xv * w0.y; acc[2] += xv * w0.z; acc[3] += xv * w0.w;
    acc[4] += xv * w1.x; acc[5] += xv * w1.y; acc[6] += xv * w1.z; acc[7] += xv * w1.w;
  }
#pragma unroll
  for (int off = 32; off > 0; off >>= 1) {
#pragma unroll
    for (int e = 0; e < 8; e++) acc[e] += __shfl_xor(acc[e], off, 64);
  }
  if (lane == 0) {
    int e0 = 0; float b0 = acc[0];
#pragma unroll
    for (int e = 1; e < 8; e++) if (acc[e] > b0) { b0 = acc[e]; e0 = e; }
    int e1 = -1; float b1 = -3.4e38f;
#pragma unroll
    for (int e = 0; e < 8; e++) if (e != e0 && acc[e] > b1) { b1 = acc[e]; e1 = e; }
    float q = expf(b1 - b0);                 // softmax denominator cancels in renorm
    float w0 = 1.0f / (1.0f + q);
    float w1 = q / (1.0f + q);
    sel_e[t * 2] = e0; sel_e[t * 2 + 1] = e1;
    sel_w[t * 2] = w0; sel_w[t * 2 + 1] = w1;
    atomicAdd(&counts[e0], 1);
    atomicAdd(&counts[e1], 1);
  }
}

__global__ void offsets_kernel(const int* __restrict__ counts,
                               int* __restrict__ offsets, int* __restrict__ cursor) {
  if (threadIdx.x == 0 && blockIdx.x == 0) {
    int s = 0;
    for (int e = 0; e < NEXP; e++) { offsets[e] = s; cursor[e] = s; s += counts[e]; }
  }
}

__global__ __launch_bounds__(256) void scatter_kernel(
    const int* __restrict__ sel_e, const float* __restrict__ sel_w,
    int* __restrict__ cursor, int* __restrict__ pair_token, float* __restrict__ pair_w) {
  int t = blockIdx.x * 256 + threadIdx.x;
#pragma unroll
  for (int j = 0; j < 2; j++) {
    int e = sel_e[t * 2 + j];
    int pos = atomicAdd(&cursor[e], 1);
    pair_token[pos] = t;
    pair_w[pos] = sel_w[t * 2 + j];
  }
}

// --- expert GEMMs: 128x256 tile, BK=32, 3-slot ring (72KB), 8 waves, 1 bar/tile ---
// Wave grid 2M x 4N, wave tile 64x64, acc[4][4] (~80 VGPR -> 4 waves/SIMD,
// 2 blocks/CU with 72KB LDS). Per K-tile (round-6 skeleton, 1 barrier):
//   vmcnt(3) [own newest 3 = t+1's, so tile t fully landed] -> s_barrier
//   [global RAW] -> 8 ds_read(slot t) -> stage t+2 (3 gload16 -> slot t-1)
//   -> setprio(1) 16 MFMA. Last tile: vmcnt(0) (round-3/4 lesson).
// WAR: stage into slot t-1 is AFTER bar(t); all reads of slot t-1 were in
// tile t-1's body, before bar(t). The round-6 second barrier guarded nothing.
// Swizzle (round-2/6 pair, measured 0 conflicts): 64B rows = 4 chunks of 16B;
// store chunk (tid&3)^((tid>>3)&3), read chunk g at slot g^((lr>>1)&3).
// Work order: w -> (nt, ks, mt) with mt fastest + XCD chunking (nb%8==0,
// bijective): consecutive blocks in an XCD share one 512KB B-panel (L2).
// Grid compaction (round 6): mt = flat 128-row tile over all experts.
template <int KD, int KSPL, int NTP, bool GATHER, bool SQRELU>
__global__ __launch_bounds__(512, 4) void moe_gemm_kernel(
    const unsigned short* __restrict__ A0, const unsigned short* __restrict__ B0,
    const int* __restrict__ counts,
    const int* __restrict__ pair_token, const float* __restrict__ pair_w,
    unsigned short* __restrict__ h1out, float* __restrict__ out) {
  constexpr int ND = SQRELU ? FFDIM : HDIM;
  constexpr int KLEN = KD / KSPL;
  constexpr int NTILES = KLEN / 32;

  // XCD-chunked bijective swizzle (gridDim.x % 8 == 0); mt fastest
  int d = blockIdx.x;
  int nb = gridDim.x;
  int w = (d & 7) * (nb >> 3) + (d >> 3);
  int mt = w % MAXMT;
  int rest = w / MAXMT;
  int ks = rest % KSPL;
  int nt = rest / KSPL;

  // ---- expert-tile search (wave-uniform) ----
  int eSel = -1, tloc = 0, segstart = 0, segcnt = 0;
  {
    int cumt = 0, acc = 0;
#pragma unroll
    for (int ee = 0; ee < NEXP; ee++) {
      int c = counts[ee];
      int ntl = (c + 127) >> 7;
      if (eSel < 0 && mt < cumt + ntl) { eSel = ee; tloc = mt - cumt; segstart = acc; segcnt = c; }
      cumt += ntl; acc += c;
    }
  }
  if (eSel < 0) return;

  const unsigned short* B = B0 + (size_t)eSel * ND * KD + (size_t)ks * KLEN;
  const unsigned short* Abase = A0 + (size_t)ks * KLEN;

  int tid = threadIdx.x;
  int lane = tid & 63;
  int wv = tid >> 6;       // 0..7
  int wr = wv >> 2;        // 0..1  (M: rows wr*64..+63)
  int wc = wv & 3;         // 0..3  (N: cols wc*64..+63)
  int g  = lane >> 4;      // 0..3
  int lr = lane & 15;

  // staging: A rows tid>>2 (0..127, 1 gload); B rows r*128 + tid>>2 (2 gloads)
  int srow = tid >> 2;                       // 0..127
  int schunk = (tid & 3) ^ ((tid >> 3) & 3); // pre-swizzled source chunk
  const unsigned short* aP;
  const unsigned short* bP[2];
  {
    int idx = tloc * 128 + srow;
    if (idx >= segcnt) idx = segcnt - 1;     // clamp pad rows
    int p = segstart + idx;
    size_t rowoff;
    if (GATHER) rowoff = (size_t)pair_token[p] * KD;
    else        rowoff = (size_t)p * KD;
    aP = Abase + rowoff + schunk * 8;
#pragma unroll
    for (int r = 0; r < 2; r++)
      bP[r] = B + (size_t)(nt * 256 + r * 128 + srow) * KD + schunk * 8;
  }

  __shared__ char lds[73728];          // 3 slots x (A 8KB + B 16KB)
  const char* ldsc = lds;
  int ldsW = wv * 1024;                // wave-uniform (lane*16 added by HW)

  f32x4 acc[4][4];
#pragma unroll
  for (int i = 0; i < 4; i++)
#pragma unroll
    for (int j = 0; j < 4; j++) acc[i][j] = (f32x4){0.f, 0.f, 0.f, 0.f};

  // per-thread LDS read bases (within a slot)
  int swz = (g ^ ((lr >> 1) & 3)) * 16;
  int abase0 = (wr * 64 + lr) * 64 + swz;            // + mi*1024
  int bbase0 = 8192 + (wc * 64 + lr) * 64 + swz;     // + nj*1024

  // prologue: stage tiles 0 and 1 into slots 0,1
#pragma unroll
  for (int t = 0; t < 2; t++) {
    int so = t * 24576;
    gload16(aP, ldsc + so + ldsW);
    gload16(bP[0], ldsc + so + 8192 + ldsW);
    gload16(bP[1], ldsc + so + 16384 + ldsW);
    aP += 32; bP[0] += 32; bP[1] += 32;
  }

  int rsOff = 0, rs2Off = 49152;
  for (int t = 0; t < NTILES; ++t) {
    // own newest 3 = t+1's loads; everything older (tile t) forced complete.
    if (t < NTILES - 1) {
      asm volatile("s_waitcnt vmcnt(3)" ::: "memory");
    } else {
      asm volatile("s_waitcnt vmcnt(0)" ::: "memory");
    }
    __builtin_amdgcn_s_barrier();
    __builtin_amdgcn_sched_barrier(0);

    short8 af[4], bf[4];
#pragma unroll
    for (int mi = 0; mi < 4; mi++)
      af[mi] = *(const short8*)(ldsc + rsOff + abase0 + mi * 1024);
#pragma unroll
    for (int nj = 0; nj < 4; nj++)
      bf[nj] = *(const short8*)(ldsc + rsOff + bbase0 + nj * 1024);

    if (t + 2 < NTILES) {              // stage tile t+2 into slot of tile t-1
      gload16(aP, ldsc + rs2Off + ldsW);
      gload16(bP[0], ldsc + rs2Off + 8192 + ldsW);
      gload16(bP[1], ldsc + rs2Off + 16384 + ldsW);
      aP += 32; bP[0] += 32; bP[1] += 32;
    }

    __builtin_amdgcn_s_setprio(1);
#pragma unroll
    for (int mi = 0; mi < 4; mi++)
#pragma unroll
      for (int nj = 0; nj < 4; nj++)
        acc[mi][nj] = __builtin_amdgcn_mfma_f32_16x16x32_bf16(af[mi], bf[nj], acc[mi][nj], 0, 0, 0);
    __builtin_amdgcn_s_setprio(0);

    rsOff  = (rsOff  == 49152) ? 0 : rsOff  + 24576;
    rs2Off = (rs2Off == 49152) ? 0 : rs2Off + 24576;
  }

  // ---- epilogue: C/D layout col=lane&15, row=(lane>>4)*4+q ----
  int colb = nt * 256 + wc * 64 + lr;        // + nj*16
  int rowb = tloc * 128 + wr * 64 + g * 4;   // + mi*16 + q
#pragma unroll
  for (int mi = 0; mi < 4; mi++) {
#pragma unroll
    for (int q = 0; q < 4; q++) {
      int idx = rowb + mi * 16 + q;
      if (idx < segcnt) {
        int p = segstart + idx;
        if (SQRELU) {
          size_t ro = (size_t)p * FFDIM + colb;
#pragma unroll
          for (int nj = 0; nj < 4; nj++) {
            float v = acc[mi][nj][q];
            v = v > 0.f ? v * v : 0.f;
            h1out[ro + nj * 16] = f2bf(v);
          }
        } else {
          int tok = pair_token[p];
          float wgt = pair_w[p];
          size_t ro = (size_t)tok * HDIM + colb;
#pragma unroll
          for (int nj = 0; nj < 4; nj++)
            atomicAdd(out + ro + nj * 16, acc[mi][nj][q] * wgt);
        }
      }
    }
  }
}

// ---------------- launch ----------------

extern "C" void kernel_launch(void* const* d_in, const int* in_sizes, int n_in,
                              void* d_out, int out_size, void* d_ws, size_t ws_size,
                              hipStream_t stream) {
  (void)in_sizes; (void)n_in; (void)out_size; (void)ws_size;
  const float* x     = (const float*)d_in[0];
  const float* Wg    = (const float*)d_in[1];
  const float* Wfc   = (const float*)d_in[2];
  const float* Wproj = (const float*)d_in[3];
  float* out = (float*)d_out;

  char* w = (char*)d_ws;
  size_t o = 0;
  auto take = [&](size_t n) { char* p = w + o; o += (n + 255) & ~(size_t)255; return p; };
  unsigned short* xb     = (unsigned short*)take((size_t)T_TOK * HDIM * 2);
  unsigned short* WfcT   = (unsigned short*)take((size_t)NEXP * FFDIM * HDIM * 2);
  unsigned short* WprojT = (unsigned short*)take((size_t)NEXP * HDIM * FFDIM * 2);
  unsigned short* h1     = (unsigned short*)take((size_t)NPAIR * FFDIM * 2);
  int*   sel_e      = (int*)take(T_TOK * 2 * 4);
  float* sel_w      = (float*)take(T_TOK * 2 * 4);
  int*   pair_token = (int*)take(NPAIR * 4);
  float* pair_w     = (float*)take(NPAIR * 4);
  int*   counts     = (int*)take(3 * 8 * 4);
  int*   offsets    = counts + 8;
  int*   cursor     = counts + 16;

  hipMemsetAsync(out, 0, (size_t)T_TOK * HDIM * 4, stream);
  hipMemsetAsync(counts, 0, 96, stream);

  convert_x_kernel<<<T_TOK * HDIM / (256 * 8), 256, 0, stream>>>(x, xb);
  transpose_bf16_kernel<<<dim3(FFDIM / 64, HDIM / 64, NEXP), 256, 0, stream>>>(Wfc, WfcT, HDIM, FFDIM);
  transpose_bf16_kernel<<<dim3(HDIM / 64, FFDIM / 64, NEXP), 256, 0, stream>>>(Wproj, WprojT, FFDIM, HDIM);
  router_kernel<<<T_TOK / 4, 256, 0, stream>>>(x, Wg, sel_e, sel_w, counts);
  offsets_kernel<<<1, 64, 0, stream>>>(counts, offsets, cursor);
  scatter_kernel<<<T_TOK / 256, 256, 0, stream>>>(sel_e, sel_w, cursor, pair_token, pair_w);

  // GEMM1: per expert, [seg x 1024] x [1024 x 4096] -> relu^2 -> h1 (bf16)
  moe_gemm_kernel<HDIM, 1, FFDIM / 256, true, true>
      <<<(FFDIM / 256) * MAXMT, 512, 0, stream>>>(xb, WfcT, counts,
                                                  pair_token, pair_w, h1, nullptr);
  // GEMM2: per expert, [seg x 4096] x [4096 x 1024] -> weighted combine, split-K=2
  moe_gemm_kernel<FFDIM, 2, HDIM / 256, false, false>
      <<<(HDIM / 256) * 2 * MAXMT, 512, 0, stream>>>(h1, WprojT, counts,
                                                     pair_token, pair_w, nullptr, out);
}